// Round 1
// baseline (296.859 us; speedup 1.0000x reference)
//
#include <hip/hip_runtime.h>

#define BB 8
#define NN 1024
#define CC 768
#define OO 768
#define RR 16
#define MM (BB*NN)      /* 8192  */
#define KK (CC*RR)      /* 12288 */
#define BM 64
#define BO 128
#define BK 64
#define KTILES (KK/BK)  /* 192 */
#define MTILES (MM/BM)  /* 128 */
#define OTILES (OO/BO)  /* 6   */
#define NBLK (MTILES*OTILES) /* 768 = 3 blocks/CU exactly */

typedef __bf16 bf16x8 __attribute__((ext_vector_type(8)));
typedef float  f32x4  __attribute__((ext_vector_type(4)));

__device__ static __forceinline__ void gl_lds16(const void* g, void* l) {
    __builtin_amdgcn_global_load_lds(
        (const __attribute__((address_space(1))) void*)g,
        (__attribute__((address_space(3))) void*)l,
        16, 0, 0);
}

// ---- prep: weight fp32 -> bf16 (ws), and bias_term[n,o] = coef[n,:]·bias[o,:] ----
__global__ __launch_bounds__(256) void k_prep(const float* __restrict__ w,
                                              const float* __restrict__ coef,
                                              const float* __restrict__ bias,
                                              __bf16* __restrict__ wbf,
                                              float* __restrict__ bterm) {
    long id = blockIdx.x;
    if (id < 4608) {                       // convert 9.44M weights, 8/thread
        long u = (id * 256 + threadIdx.x) * 8;
        float4 a = *(const float4*)(w + u);
        float4 b = *(const float4*)(w + u + 4);
        bf16x8 v = {(__bf16)a.x, (__bf16)a.y, (__bf16)a.z, (__bf16)a.w,
                    (__bf16)b.x, (__bf16)b.y, (__bf16)b.z, (__bf16)b.w};
        *(bf16x8*)(wbf + u) = v;
    } else {                               // bias_term: 1024*768 dots of length 16
        int i = (int)(id - 4608) * 256 + threadIdx.x;
        int n = i / OO, o = i - n * OO;
        float s = 0.f;
#pragma unroll
        for (int r = 0; r < RR; ++r) s += coef[n * RR + r] * bias[o * RR + r];
        bterm[i] = s;
    }
}

// ---- main GEMM: out[m,o] = sum_k A[m,k]*W[o,k] + bterm[n,o] ----
// A built on the fly: A[m, c*16+r] = x[m,c] * coef[n,r]
// BM=64 x BO=128 -> 768 blocks = 3 blocks/CU balanced; double-buffered LDS,
// ONE barrier per K-tile: stage(t+1) || build-A(t+1) || compute(t).
__global__ __launch_bounds__(256, 3) void k_gemm(const float* __restrict__ x,
                                                 const float* __restrict__ coef,
                                                 const __bf16* __restrict__ wbf,
                                                 const float* __restrict__ bterm,
                                                 float* __restrict__ out) {
    __shared__ __bf16 lA[2][BM * BK];   // 2 x 8 KB
    __shared__ __bf16 lB[2][BO * BK];   // 2 x 16 KB

    const int tid = threadIdx.x;

    // XCD swizzle, otile-major: each XCD's 96 resident blocks span <=2 otiles
    // (W working set per XCD <=6MB instead of 18.9MB). 768 % 8 == 0 -> bijective.
    int bid  = blockIdx.x;
    int swz  = (bid & 7) * (NBLK / 8) + (bid >> 3);
    int otile = swz >> 7;        // 0..5
    int mtile = swz & 127;       // 0..127
    const int m0 = mtile * BM, o0 = otile * BO;

    // ---- A-build mapping: thread -> (row am, c-position ac) ----
    const int am = tid & 63;            // row 0..63
    const int ac = tid >> 6;            // c slot 0..3 within the K-tile
    const int m_glob = m0 + am;
    const int n_idx  = m_glob & (NN - 1);
    const float* xrow = x + (long)m_glob * CC;

    float cf[16];
#pragma unroll
    for (int r = 0; r < 16; r += 4) {
        float4 t4 = *(const float4*)(coef + n_idx * RR + r);
        cf[r] = t4.x; cf[r + 1] = t4.y; cf[r + 2] = t4.z; cf[r + 3] = t4.w;
    }

    // ---- wave / fragment mapping ----
    const int lane = tid & 63, wave = tid >> 6;
    const int wr = wave & 1, wc = wave >> 1;    // wave tile: 32(m) x 64(o)
    const int lrow = lane & 15, quad = lane >> 4;

    f32x4 acc[2][4] = {};

    // stage B-tile kt into buffer b (async DMA, global-side XOR swizzle)
    auto STAGE = [&](int b, int kt) {
#pragma unroll
        for (int s = 0; s < 4; ++s) {
            int u = s * 256 + tid;              // 1024 chunks of 16B
            int row = u >> 3, cl = u & 7;
            int g = cl ^ (row & 7);             // logical chunk stored at LDS chunk cl
            const __bf16* gp = wbf + (long)(o0 + row) * KK + kt * BK + g * 8;
            gl_lds16(gp, ((char*)lB[b]) + u * 16);
        }
    };
    // build A-tile (1 c x 16 r per thread -> 2 swizzled 16B chunks)
    auto BUILD = [&](int b, float xv) {
#pragma unroll
        for (int rh = 0; rh < 2; ++rh) {
            bf16x8 v;
#pragma unroll
            for (int j = 0; j < 8; ++j) v[j] = (__bf16)(xv * cf[rh * 8 + j]);
            int kb  = ac * 2 + rh;              // logical chunk 0..7
            int kbs = kb ^ (am & 7);            // swizzled slot
            *(bf16x8*)(&lA[b][am * BK + kbs * 8]) = v;
        }
    };

    // ---- prologue: tile 0 ----
    float xv = xrow[ac];
    STAGE(0, 0);
    float xn = xrow[4 + ac];
    BUILD(0, xv);
    __syncthreads();

#pragma unroll 2
    for (int kt = 0; kt < KTILES; ++kt) {
        const int cur = kt & 1;
        if (kt + 1 < KTILES) {
            STAGE(cur ^ 1, kt + 1);             // DMA issued early, drained at the
            BUILD(cur ^ 1, xn);                 // end-of-iter barrier (overlaps compute)
            int nc = (kt + 2 < KTILES) ? (kt + 2) : (KTILES - 1);
            xn = xrow[nc * 4 + ac];
        }
        // ---- compute tile kt: 2 k-steps x 8 MFMA ----
#pragma unroll
        for (int ks = 0; ks < 2; ++ks) {
            bf16x8 af[2], bfr[4];
            int kb = ks * 4 + quad;
#pragma unroll
            for (int im = 0; im < 2; ++im) {
                int row = wr * 32 + im * 16 + lrow;
                af[im] = *(const bf16x8*)(&lA[cur][row * BK + (kb ^ (row & 7)) * 8]);
            }
#pragma unroll
            for (int io = 0; io < 4; ++io) {
                int row = wc * 64 + io * 16 + lrow;
                bfr[io] = *(const bf16x8*)(&lB[cur][row * BK + (kb ^ (row & 7)) * 8]);
            }
#pragma unroll
            for (int im = 0; im < 2; ++im)
#pragma unroll
                for (int io = 0; io < 4; ++io)
                    acc[im][io] = __builtin_amdgcn_mfma_f32_16x16x32_bf16(
                        af[im], bfr[io], acc[im][io], 0, 0, 0);
        }
        __syncthreads();   // single barrier/iter: drains next-tile DMA + A ds_writes,
                           // and protects buffers before reuse
    }

    // ---- epilogue: D col=lane&15 (o), row=(lane>>4)*4+reg (m); add bias_term ----
    const int nbase = m0 & (NN - 1);
#pragma unroll
    for (int im = 0; im < 2; ++im) {
#pragma unroll
        for (int io = 0; io < 4; ++io) {
            int o = o0 + wc * 64 + io * 16 + lrow;
#pragma unroll
            for (int r = 0; r < 4; ++r) {
                int moff = wr * 32 + im * 16 + quad * 4 + r;
                long m = m0 + moff;
                out[m * OO + o] = acc[im][io][r] + bterm[(nbase + moff) * OO + o];
            }
        }
    }
}

// ---- fallback if workspace too small (correctness-only) ----
__global__ void k_naive(const float* __restrict__ x, const float* __restrict__ coef,
                        const float* __restrict__ w, const float* __restrict__ bias,
                        float* __restrict__ out) {
    long i = (long)blockIdx.x * 256 + threadIdx.x;
    if (i >= (long)MM * OO) return;
    int o = (int)(i % OO);
    long m = i / OO;
    int n = (int)(m & (NN - 1));
    float cf[16];
#pragma unroll
    for (int r = 0; r < 16; ++r) cf[r] = coef[n * RR + r];
    const float* xr = x + m * CC;
    const float* wr = w + (long)o * CC * RR;
    float s = 0.f;
    for (int c = 0; c < CC; ++c) {
        float t = 0.f;
#pragma unroll
        for (int r = 0; r < 16; ++r) t += cf[r] * wr[c * RR + r];
        s += xr[c] * t;
    }
    float bs = 0.f;
#pragma unroll
    for (int r = 0; r < 16; ++r) bs += cf[r] * bias[o * RR + r];
    out[i] = s + bs;
}

extern "C" void kernel_launch(void* const* d_in, const int* in_sizes, int n_in,
                              void* d_out, int out_size, void* d_ws, size_t ws_size,
                              hipStream_t stream) {
    const float* x    = (const float*)d_in[0];
    const float* coef = (const float*)d_in[1];
    const float* w    = (const float*)d_in[2];
    const float* bias = (const float*)d_in[3];
    float* out = (float*)d_out;

    const size_t wbf_bytes = (size_t)OO * KK * sizeof(__bf16);   // 18,874,368
    const size_t bt_bytes  = (size_t)NN * OO * sizeof(float);    //  3,145,728

    if (ws_size >= wbf_bytes + bt_bytes) {
        __bf16* wbf  = (__bf16*)d_ws;
        float*  btrm = (float*)((char*)d_ws + wbf_bytes);
        k_prep<<<7680, 256, 0, stream>>>(w, coef, bias, wbf, btrm);
        k_gemm<<<NBLK, 256, 0, stream>>>(x, coef, wbf, btrm, out);
    } else {
        k_naive<<<(int)(((long)MM * OO + 255) / 256), 256, 0, stream>>>(x, coef, w, bias, out);
    }
}